// Round 13
// baseline (280.151 us; speedup 1.0000x reference)
//
#include <hip/hip_runtime.h>
#include <hip/hip_bf16.h>

// Problem: B=2, N=2048, D=2048, h=16, hd=128.  All dims hardcoded.
// Pipeline: cvt3 ; rope tables ; GEMM1 = 8-phase 256^2 (m201 template; launch_bounds(512,1)
// so the 128-VGPR acc cannot trigger the 128-cap spill that corrupted vmcnt in r2) ->
// qkv linear ; rope+head-transpose ; flash attention (r10 structure — no cross-strip
// operand sharing, 4 spills say no) ; GEMM2 (fp32 + bias, m97-family).

typedef unsigned short u16;
typedef short bf16x8 __attribute__((ext_vector_type(8)));
typedef unsigned short u16x8 __attribute__((ext_vector_type(8)));
typedef float f32x4 __attribute__((ext_vector_type(4)));

#define MFMA16(a, b, c) __builtin_amdgcn_mfma_f32_16x16x32_bf16((a), (b), (c), 0, 0, 0)
#define BAR() asm volatile("s_barrier" ::: "memory")
#define WAITV(N) asm volatile("s_waitcnt vmcnt(" #N ")" ::: "memory")
#define WAITL0()                                       \
    asm volatile("s_waitcnt lgkmcnt(0)" ::: "memory"); \
    __builtin_amdgcn_sched_barrier(0)

__device__ __forceinline__ float b2f(u16 u) { return __uint_as_float(((unsigned)u) << 16); }
__device__ __forceinline__ u16 f2b(float f) {
    unsigned x = __float_as_uint(f);
    return (u16)((x + 0x7fffu + ((x >> 16) & 1u)) >> 16);
}
__device__ __forceinline__ void gload16(const u16* g, u16* lds) {
    __builtin_amdgcn_global_load_lds((__attribute__((address_space(1))) void*)g,
                                     (__attribute__((address_space(3))) void*)lds,
                                     16, 0, 0);
}

// ---------------- fp32 -> bf16 conversion, all three tensors in one dispatch ----------
__global__ __launch_bounds__(256) void cvt3(const float* __restrict__ x,
                                            const float* __restrict__ wqkv,
                                            const float* __restrict__ wproj,
                                            u16* __restrict__ xo, u16* __restrict__ qo,
                                            u16* __restrict__ po) {
    const int bx = blockIdx.x;
    const float* src;
    u16* dst;
    size_t base;
    if (bx < 4096) {
        src = x; dst = xo; base = (size_t)bx * 256;
    } else if (bx < 10240) {
        src = wqkv; dst = qo; base = (size_t)(bx - 4096) * 256;
    } else {
        src = wproj; dst = po; base = (size_t)(bx - 10240) * 256;
    }
    size_t i = base + threadIdx.x;
    float4 a = ((const float4*)src)[2 * i];
    float4 b = ((const float4*)src)[2 * i + 1];
    u16x8 o;
    o[0] = f2b(a.x); o[1] = f2b(a.y); o[2] = f2b(a.z); o[3] = f2b(a.w);
    o[4] = f2b(b.x); o[5] = f2b(b.y); o[6] = f2b(b.z); o[7] = f2b(b.w);
    ((u16x8*)dst)[i] = o;
}

// ---------------- RoPE tables ----------------
__global__ __launch_bounds__(256) void rope_tables_k(float* __restrict__ cosT,
                                                     float* __restrict__ sinT) {
    int idx = blockIdx.x * 256 + threadIdx.x;  // 131072 total
    int n = idx >> 6, i = idx & 63;
    float inv = powf(10000.0f, -(float)(2 * i) / 128.0f);
    float ang = (float)n * inv;
    cosT[idx] = cosf(ang);
    sinT[idx] = sinf(ang);
}

// ================= 8-phase 256^2 NT GEMM (m201 template, bf16 out) =================
// BM=BN=256, BK=64, 512 thr (8 waves 2Mx4N), per-wave C 128x64, LDS 128KiB (1 block/CU).
// LDS: [2 dbuf][2 khalf][256 rows][4 chunks of 16B]; global_load_lds linear dest with
// pre-swizzled SOURCE chunk = slot ^ ((row>>1)&3) (rule 21); frag READ applies same XOR
// -> 2-way max on b128 reads.  Stage schedule per iter (tiles t,t+1): ph1 A[t+1].k1;
// ph2 B[t+2].k0; ph3 A[t+2].k0; ph4 B[t+2].k1 +vmcnt(6); ph5 A[t+2].k1; ph6 B[t+3].k0;
// ph7 A[t+3].k0; ph8 B[t+3].k1 +vmcnt(6).  Hazards audited r2/r13: every read covered by
// a vmcnt(6) >=4 stage-ops later; every overwrite >=1 barrier-pair after last read.
// launch_bounds(512,1): VGPR cap 512 — acc[8][4] alone is 128 VGPR; the r2 failure is
// attributed to the compiler's 128-cap choice spilling in-loop (scratch VMEM corrupts
// the hand-counted vmcnt).  Verify via counters: WRITE_SIZE must be exactly qkv.
template <int MB>
__device__ __forceinline__ void quad(f32x4 (&acc)[8][4], const bf16x8 (&af)[4],
                                     const bf16x8 (&bf)[4]) {
#pragma unroll
    for (int j = 0; j < 4; ++j)
#pragma unroll
        for (int n = 0; n < 4; ++n)
            acc[MB * 4 + j][n] = MFMA16(af[j], bf[n], acc[MB * 4 + j][n]);
}

__global__ __launch_bounds__(512, 1) void gemm8_nt(const u16* __restrict__ A,
                                                   const u16* __restrict__ B,
                                                   u16* __restrict__ C,
                                                   int M, int Nc, int K, int ntn) {
    __shared__ __align__(16) u16 AS[2][2][256 * 32];
    __shared__ __align__(16) u16 BS[2][2][256 * 32];
    const int tx = threadIdx.x;
    const int w = tx >> 6, l = tx & 63;
    const int fr = l & 15, fg = l >> 4;
    const int wr = w >> 2, wc = w & 3;
    const int id = blockIdx.x;  // no XCD swizzle (r9: it doubled FETCH)
    const int tm = id / ntn, tn = id % ntn;
    const size_t row0 = (size_t)tm * 256, col0 = (size_t)tn * 256;
    const u16* Ab = A + row0 * (size_t)K;
    const u16* Bb = B + col0 * (size_t)K;
    const int nt = K >> 6, tmask = nt - 1;

    const int r0c = tx >> 2, s0 = (tx & 3) ^ ((r0c >> 1) & 3);
    const int r1c = (512 + tx) >> 2, s1 = ((512 + tx) & 3) ^ ((r1c >> 1) & 3);
    const int d0 = (w * 64) * 8, d1 = (512 + w * 64) * 8;
    auto stage = [&](const u16* src, u16* reg) {
        gload16(src + (size_t)r0c * K + s0 * 8, reg + d0);
        gload16(src + (size_t)r1c * K + s1 * 8, reg + d1);
    };
    auto frag = [&](const u16* reg, int r) {
        return *(const bf16x8*)&reg[r * 32 + ((fg ^ ((r >> 1) & 3)) << 3)];
    };

    f32x4 acc[8][4] = {};
    const int a0 = wr * 128, b0c = wc * 64;

    // prologue: tile0 {Bk0,Ak0,Bk1,Ak1}, tile1 {Bk0,Ak0,Bk1}  (7 half-tiles)
    stage(Bb + 0, BS[0][0]);
    stage(Ab + 0, AS[0][0]);
    stage(Bb + 32, BS[0][1]);
    stage(Ab + 32, AS[0][1]);
    stage(Bb + 64, BS[1][0]);
    stage(Ab + 64, AS[1][0]);
    stage(Bb + 64 + 32, BS[1][1]);
    WAITV(6);  // tile0 fully landed
    BAR();

    bf16x8 afrag[4], bfrag[4];
    for (int i = 0; i < (nt >> 1); ++i) {
        const int t = 2 * i;
        const size_t o1 = (size_t)((t + 1) & tmask) * 64;
        const size_t o2 = (size_t)((t + 2) & tmask) * 64;
        const size_t o3 = (size_t)((t + 3) & tmask) * 64;
        // ph1: buf0.k0 quad0 ; stage A[t+1].k1
#pragma unroll
        for (int j = 0; j < 4; ++j) afrag[j] = frag(AS[0][0], a0 + j * 16 + fr);
#pragma unroll
        for (int n = 0; n < 4; ++n) bfrag[n] = frag(BS[0][0], b0c + n * 16 + fr);
        stage(Ab + o1 + 32, AS[1][1]);
        BAR(); WAITL0();
        __builtin_amdgcn_s_setprio(1); quad<0>(acc, afrag, bfrag); __builtin_amdgcn_s_setprio(0);
        BAR();
        // ph2: buf0.k0 quad1 ; stage B[t+2].k0
#pragma unroll
        for (int j = 0; j < 4; ++j) afrag[j] = frag(AS[0][0], a0 + 64 + j * 16 + fr);
        stage(Bb + o2, BS[0][0]);
        BAR(); WAITL0();
        __builtin_amdgcn_s_setprio(1); quad<1>(acc, afrag, bfrag); __builtin_amdgcn_s_setprio(0);
        BAR();
        // ph3: buf0.k1 quad0 ; stage A[t+2].k0
#pragma unroll
        for (int j = 0; j < 4; ++j) afrag[j] = frag(AS[0][1], a0 + j * 16 + fr);
#pragma unroll
        for (int n = 0; n < 4; ++n) bfrag[n] = frag(BS[0][1], b0c + n * 16 + fr);
        stage(Ab + o2, AS[0][0]);
        BAR(); WAITL0();
        __builtin_amdgcn_s_setprio(1); quad<0>(acc, afrag, bfrag); __builtin_amdgcn_s_setprio(0);
        BAR();
        // ph4: buf0.k1 quad1 ; stage B[t+2].k1 ; vmcnt(6)
#pragma unroll
        for (int j = 0; j < 4; ++j) afrag[j] = frag(AS[0][1], a0 + 64 + j * 16 + fr);
        stage(Bb + o2 + 32, BS[0][1]);
        WAITV(6);
        BAR(); WAITL0();
        __builtin_amdgcn_s_setprio(1); quad<1>(acc, afrag, bfrag); __builtin_amdgcn_s_setprio(0);
        BAR();
        // ph5: buf1.k0 quad0 ; stage A[t+2].k1
#pragma unroll
        for (int j = 0; j < 4; ++j) afrag[j] = frag(AS[1][0], a0 + j * 16 + fr);
#pragma unroll
        for (int n = 0; n < 4; ++n) bfrag[n] = frag(BS[1][0], b0c + n * 16 + fr);
        stage(Ab + o2 + 32, AS[0][1]);
        BAR(); WAITL0();
        __builtin_amdgcn_s_setprio(1); quad<0>(acc, afrag, bfrag); __builtin_amdgcn_s_setprio(0);
        BAR();
        // ph6: buf1.k0 quad1 ; stage B[t+3].k0
#pragma unroll
        for (int j = 0; j < 4; ++j) afrag[j] = frag(AS[1][0], a0 + 64 + j * 16 + fr);
        stage(Bb + o3, BS[1][0]);
        BAR(); WAITL0();
        __builtin_amdgcn_s_setprio(1); quad<1>(acc, afrag, bfrag); __builtin_amdgcn_s_setprio(0);
        BAR();
        // ph7: buf1.k1 quad0 ; stage A[t+3].k0
#pragma unroll
        for (int j = 0; j < 4; ++j) afrag[j] = frag(AS[1][1], a0 + j * 16 + fr);
#pragma unroll
        for (int n = 0; n < 4; ++n) bfrag[n] = frag(BS[1][1], b0c + n * 16 + fr);
        stage(Ab + o3, AS[1][0]);
        BAR(); WAITL0();
        __builtin_amdgcn_s_setprio(1); quad<0>(acc, afrag, bfrag); __builtin_amdgcn_s_setprio(0);
        BAR();
        // ph8: buf1.k1 quad1 ; stage B[t+3].k1 ; vmcnt(6)
#pragma unroll
        for (int j = 0; j < 4; ++j) afrag[j] = frag(AS[1][1], a0 + 64 + j * 16 + fr);
        stage(Bb + o3 + 32, BS[1][1]);
        WAITV(6);
        BAR(); WAITL0();
        __builtin_amdgcn_s_setprio(1); quad<1>(acc, afrag, bfrag); __builtin_amdgcn_s_setprio(0);
        BAR();
    }
    asm volatile("s_waitcnt vmcnt(0)" ::: "memory");  // drain wrapped prefetches
#pragma unroll
    for (int m = 0; m < 8; ++m)
#pragma unroll
        for (int n = 0; n < 4; ++n)
#pragma unroll
            for (int rr = 0; rr < 4; ++rr) {
                size_t row = row0 + a0 + m * 16 + fg * 4 + rr;
                size_t col = col0 + b0c + n * 16 + fr;
                C[row * (size_t)Nc + col] = f2b(acc[m][n][rr]);
            }
}

// ---------------- RoPE apply + head transpose ----------------
__global__ __launch_bounds__(256) void rope_transpose_k(
    const u16* __restrict__ qkv, const float* __restrict__ cosT,
    const float* __restrict__ sinT, u16* __restrict__ Q, u16* __restrict__ Ko,
    u16* __restrict__ VT) {
    const int bh = blockIdx.y, b = bh >> 4, h = bh & 15;
    const int n0 = blockIdx.x << 7;
    const int tx = threadIdx.x;
    __shared__ u16 vbuf[128][136];
    const float SCALE = 0.08838834764831844f;  // 1/sqrt(128)
#pragma unroll
    for (int pass = 0; pass < 4; ++pass) {
        const int rr = pass * 32 + (tx >> 3);
        const int p = tx & 7;
        const int n = n0 + rr;
        const u16* src = qkv + ((size_t)(b * 2048 + n)) * 6144 + h * 128;
        float c[8], s[8];
#pragma unroll
        for (int j = 0; j < 8; ++j) {
            c[j] = cosT[n * 64 + p * 8 + j];
            s[j] = sinT[n * 64 + p * 8 + j];
        }
        {
            u16x8 t1 = *(const u16x8*)&src[p * 8];
            u16x8 t2 = *(const u16x8*)&src[64 + p * 8];
            u16x8 o1, o2;
#pragma unroll
            for (int j = 0; j < 8; ++j) {
                float a = b2f(t1[j]), bb = b2f(t2[j]);
                o1[j] = f2b((a * c[j] - bb * s[j]) * SCALE);
                o2[j] = f2b((a * s[j] + bb * c[j]) * SCALE);
            }
            u16* dst = Q + ((size_t)bh * 2048 + n) * 128;
            *(u16x8*)&dst[p * 8] = o1;
            *(u16x8*)&dst[64 + p * 8] = o2;
        }
        {
            u16x8 t1 = *(const u16x8*)&src[2048 + p * 8];
            u16x8 t2 = *(const u16x8*)&src[2048 + 64 + p * 8];
            u16x8 o1, o2;
#pragma unroll
            for (int j = 0; j < 8; ++j) {
                float a = b2f(t1[j]), bb = b2f(t2[j]);
                o1[j] = f2b(a * c[j] - bb * s[j]);
                o2[j] = f2b(a * s[j] + bb * c[j]);
            }
            u16* dst = Ko + ((size_t)bh * 2048 + n) * 128;
            *(u16x8*)&dst[p * 8] = o1;
            *(u16x8*)&dst[64 + p * 8] = o2;
        }
    }
#pragma unroll
    for (int i = 0; i < 8; ++i) {
        int cid = i * 256 + tx;
        int rr = cid >> 4, cc = cid & 15;
        *(u16x8*)&vbuf[rr][cc * 8] =
            *(const u16x8*)&qkv[((size_t)(b * 2048 + n0 + rr)) * 6144 + 4096 + h * 128 + cc * 8];
    }
    __syncthreads();
#pragma unroll
    for (int i = 0; i < 8; ++i) {
        int cid = i * 256 + tx;
        int j = cid >> 4, nc = cid & 15;
        u16x8 o;
#pragma unroll
        for (int e = 0; e < 8; ++e) o[e] = vbuf[nc * 8 + e][j];
        *(u16x8*)&VT[((size_t)bh * 128 + j) * 2048 + n0 + nc * 8] = o;
    }
}

// ---------------- NT GEMM (BK=64, conflict-free) for GEMM2 ----------------
__global__ __launch_bounds__(256, 2) void gemm_nt_f32(const u16* __restrict__ A,
                                                      const u16* __restrict__ B,
                                                      float* __restrict__ C,
                                                      const float* __restrict__ bias,
                                                      int Ncols, int K) {
    __shared__ u16 As[128 * 64];
    __shared__ u16 Bs[128 * 64];
    const int tx = threadIdx.x;
    const int w = tx >> 6, l = tx & 63;
    const int fr = l & 15, fg = l >> 4;
    const int wr = w >> 1, wc = w & 1;
    const long row0 = (long)blockIdx.x * 128;
    const long col0 = (long)blockIdx.y * 128;
    f32x4 acc[4][4] = {};
    const int nk = K >> 6;
    int rs[4], ss[4];
#pragma unroll
    for (int i = 0; i < 4; ++i) {
        int c = i * 256 + tx;
        rs[i] = c >> 3;
        ss[i] = (c & 7) ^ ((c >> 3) & 7);
    }
    for (int kt = 0; kt < nk; ++kt) {
        const long k0 = (long)kt << 6;
        __syncthreads();
#pragma unroll
        for (int i = 0; i < 4; ++i)
            gload16(A + (row0 + rs[i]) * K + k0 + ss[i] * 8, &As[(i * 256 + w * 64) * 8]);
#pragma unroll
        for (int i = 0; i < 4; ++i)
            gload16(B + (col0 + rs[i]) * K + k0 + ss[i] * 8, &Bs[(i * 256 + w * 64) * 8]);
        __syncthreads();
#pragma unroll
        for (int kk = 0; kk < 2; ++kk) {
            bf16x8 af[4], bfv[4];
#pragma unroll
            for (int m = 0; m < 4; ++m) {
                int r = wr * 64 + m * 16 + fr;
                af[m] = *(const bf16x8*)&As[r * 64 + (((kk * 4 + fg) ^ (r & 7)) << 3)];
            }
#pragma unroll
            for (int n = 0; n < 4; ++n) {
                int r = wc * 64 + n * 16 + fr;
                bfv[n] = *(const bf16x8*)&Bs[r * 64 + (((kk * 4 + fg) ^ (r & 7)) << 3)];
            }
#pragma unroll
            for (int m = 0; m < 4; ++m)
#pragma unroll
                for (int n = 0; n < 4; ++n) acc[m][n] = MFMA16(af[m], bfv[n], acc[m][n]);
        }
    }
#pragma unroll
    for (int m = 0; m < 4; ++m)
#pragma unroll
        for (int n = 0; n < 4; ++n)
#pragma unroll
            for (int r = 0; r < 4; ++r) {
                long row = row0 + wr * 64 + m * 16 + fg * 4 + r;
                long col = col0 + wc * 64 + n * 16 + fr;
                C[row * Ncols + col] = acc[m][n][r] + bias[col];
            }
}

// ---------------- Flash attention (r10 structure: paired strips + fast-path) ----------
__global__ __launch_bounds__(256, 2) void attn_k(const u16* __restrict__ Q,
                                                 const u16* __restrict__ K,
                                                 const u16* __restrict__ VT,
                                                 u16* __restrict__ O,
                                                 const int* __restrict__ L) {
    const int bh = blockIdx.y, b = bh >> 4, h = bh & 15;
    const int qx = blockIdx.x;
    const int qb0 = qx << 6, qb1 = (31 - qx) << 6;
    const int tx = threadIdx.x;
    const int w = tx >> 6, l = tx & 63;
    const int fr = l & 15, fg = l >> 4;
    const int Lb = L[b];
    __shared__ u16 Ks[2][64 * 128];
    __shared__ u16 Vs[2][128 * 64];
    __shared__ u16 Ps[4][16 * 72];
    const u16* Qh = Q + (size_t)bh * 2048 * 128;
    const u16* Kh = K + (size_t)bh * 2048 * 128;
    const u16* Vh = VT + (size_t)bh * 128 * 2048;
    bf16x8 aq0[4], aq1[4];
#pragma unroll
    for (int kc = 0; kc < 4; ++kc) {
        aq0[kc] = *(const bf16x8*)&Qh[(size_t)(qb0 + w * 16 + fr) * 128 + kc * 32 + fg * 8];
        aq1[kc] = *(const bf16x8*)&Qh[(size_t)(qb1 + w * 16 + fr) * 128 + kc * 32 + fg * 8];
    }
    f32x4 accO0[8] = {}, accO1[8] = {};
    float mr0[4] = {-1e30f, -1e30f, -1e30f, -1e30f};
    float mr1[4] = {-1e30f, -1e30f, -1e30f, -1e30f};
    float sr0[4] = {0.f, 0.f, 0.f, 0.f};
    float sr1[4] = {0.f, 0.f, 0.f, 0.f};
    const int kmax = min(qb1 + 63, Lb - 1);
    const int nkt = (kmax >> 6) + 1;

    auto stage_tile = [&](int kt0, int buf) {
#pragma unroll
        for (int i = 0; i < 4; ++i) {
            int c = i * 256 + tx;
            int row = c >> 4, cp = c & 15;
            gload16(Kh + (size_t)(kt0 + row) * 128 + ((cp ^ (row & 7)) << 3),
                    &Ks[buf][(i * 256 + w * 64) * 8]);
        }
#pragma unroll
        for (int i = 0; i < 4; ++i) {
            int c = i * 256 + tx;
            int row = c >> 3, cp = c & 7;
            gload16(Vh + (size_t)row * 2048 + kt0 + ((cp ^ (row & 7)) << 3),
                    &Vs[buf][(i * 256 + w * 64) * 8]);
        }
    };

    auto do_strip = [&](const bf16x8 (&aqs)[4], float (&mr)[4], float (&sr)[4],
                        f32x4 (&aO)[8], int qgb, int kt0, const u16* Ksb,
                        const u16* Vsb) {
        f32x4 accS[4];
#pragma unroll
        for (int st = 0; st < 4; ++st) {
            f32x4 z = {0.f, 0.f, 0.f, 0.f};
            accS[st] = z;
            int key = st * 16 + fr;
#pragma unroll
            for (int kc = 0; kc < 4; ++kc) {
                bf16x8 bk = *(const bf16x8*)&Ksb[key * 128 + (((kc * 4 + fg) ^ (key & 7)) << 3)];
                accS[st] = MFMA16(aqs[kc], bk, accS[st]);
            }
        }
        float sv[4][4];
        if ((kt0 + 63 <= qgb) && (kt0 + 63 < Lb)) {
#pragma unroll
            for (int st = 0; st < 4; ++st)
#pragma unroll
                for (int r = 0; r < 4; ++r) sv[st][r] = accS[st][r];
        } else {
#pragma unroll
            for (int st = 0; st < 4; ++st)
#pragma unroll
                for (int r = 0; r < 4; ++r) {
                    int key = kt0 + st * 16 + fr;
                    int qg = qgb + fg * 4 + r;
                    sv[st][r] = (key <= qg && key < Lb) ? accS[st][r] : -1e30f;
                }
        }
        float alpha[4], pr[4][4];
#pragma unroll
        for (int r = 0; r < 4; ++r) {
            float lm = fmaxf(fmaxf(sv[0][r], sv[1][r]), fmaxf(sv[2][r], sv[3][r]));
            lm = fmaxf(lm, __shfl_xor(lm, 1));
            lm = fmaxf(lm, __shfl_xor(lm, 2));
            lm = fmaxf(lm, __shfl_xor(lm, 4));
            lm = fmaxf(lm, __shfl_xor(lm, 8));
            float mn = fmaxf(mr[r], lm);
            alpha[r] = exp2f((mr[r] - mn) * 1.44269504f);
            float ls = 0.f;
#pragma unroll
            for (int st = 0; st < 4; ++st) {
                float p = exp2f((sv[st][r] - mn) * 1.44269504f);
                pr[st][r] = p;
                ls += p;
            }
            ls += __shfl_xor(ls, 1);
            ls += __shfl_xor(ls, 2);
            ls += __shfl_xor(ls, 4);
            ls += __shfl_xor(ls, 8);
            sr[r] = sr[r] * alpha[r] + ls;
            mr[r] = mn;
        }
#pragma unroll
        for (int n = 0; n < 8; ++n)
#pragma unroll
            for (int r = 0; r < 4; ++r) aO[n][r] *= alpha[r];
#pragma unroll
        for (int st = 0; st < 4; ++st)
#pragma unroll
            for (int r = 0; r < 4; ++r)
                Ps[w][(fg * 4 + r) * 72 + st * 16 + fr] = f2b(pr[st][r]);
#pragma unroll
        for (int ks = 0; ks < 2; ++ks) {
            bf16x8 ap = *(const bf16x8*)&Ps[w][fr * 72 + ks * 32 + fg * 8];
#pragma unroll
            for (int n = 0; n < 8; ++n) {
                int d = n * 16 + fr;
                bf16x8 bv = *(const bf16x8*)&Vsb[d * 64 + (((ks * 4 + fg) ^ (d & 7)) << 3)];
                aO[n] = MFMA16(ap, bv, aO[n]);
            }
        }
    };

    stage_tile(0, 0);
    int cur = 0;
    for (int kt = 0; kt < nkt; ++kt) {
        const int kt0 = kt << 6;
        __syncthreads();
        if (kt + 1 < nkt) stage_tile((kt + 1) << 6, cur ^ 1);
        if (kt <= qx)
            do_strip(aq0, mr0, sr0, accO0, qb0 + w * 16, kt0, Ks[cur], Vs[cur]);
        do_strip(aq1, mr1, sr1, accO1, qb1 + w * 16, kt0, Ks[cur], Vs[cur]);
        cur ^= 1;
    }
    float inv0[4], inv1[4];
#pragma unroll
    for (int r = 0; r < 4; ++r) {
        inv0[r] = 1.0f / sr0[r];
        inv1[r] = 1.0f / sr1[r];
    }
#pragma unroll
    for (int n = 0; n < 8; ++n)
#pragma unroll
        for (int r = 0; r < 4; ++r) {
            int d = n * 16 + fr;
            int q0 = qb0 + w * 16 + fg * 4 + r;
            int q1 = qb1 + w * 16 + fg * 4 + r;
            O[((size_t)(b * 2048 + q0)) * 2048 + h * 128 + d] = f2b(accO0[n][r] * inv0[r]);
            O[((size_t)(b * 2048 + q1)) * 2048 + h * 128 + d] = f2b(accO1[n][r] * inv1[r]);
        }
}

extern "C" void kernel_launch(void* const* d_in, const int* in_sizes, int n_in,
                              void* d_out, int out_size, void* d_ws, size_t ws_size,
                              hipStream_t stream) {
    const float* x = (const float*)d_in[0];
    const float* Wqkv = (const float*)d_in[1];
    const float* Wproj = (const float*)d_in[2];
    const float* bproj = (const float*)d_in[3];
    const int* L = (const int*)d_in[4];
    float* out = (float*)d_out;

    char* p = (char*)d_ws;
    u16* xbf = (u16*)(p + 0);                // reused as Ob after GEMM1
    u16* wqkvbf = (u16*)(p + 16777216);      // reused as Qb after GEMM1
    u16* wprojbf = (u16*)(p + 41943040);
    u16* qkv = (u16*)(p + 50331648);
    u16* Kb = (u16*)(p + 100663296);
    u16* VTb = (u16*)(p + 117440512);
    float* cosT = (float*)(p + 134217728);
    float* sinT = (float*)(p + 134742016);
    u16* Ob = xbf;
    u16* Qb = wqkvbf;

    cvt3<<<12288, 256, 0, stream>>>(x, Wqkv, Wproj, xbf, wqkvbf, wprojbf);
    rope_tables_k<<<512, 256, 0, stream>>>(cosT, sinT);
    gemm8_nt<<<384, 512, 0, stream>>>(xbf, wqkvbf, qkv, 4096, 6144, 2048, 24);
    rope_transpose_k<<<dim3(16, 32), 256, 0, stream>>>(qkv, cosT, sinT, Qb, Kb, VTb);
    attn_k<<<dim3(16, 32), 256, 0, stream>>>(Qb, Kb, VTb, Ob, L);
    gemm_nt_f32<<<dim3(32, 16), 256, 0, stream>>>(Ob, wprojbf, out, bproj, 2048, 2048);
}

// Round 14
// 237.867 us; speedup vs baseline: 1.1778x; 1.1778x over previous
//
#include <hip/hip_runtime.h>
#include <hip/hip_bf16.h>

// Problem: B=2, N=2048, D=2048, h=16, hd=128.  All dims hardcoded.
// Pipeline: cvt3+tables (one dispatch) ; GEMM1 fused (m97-family BK=64 conflict-free;
// epilogue ropes q/k + transposes v) ; flash attention (paired strips, dbuf, fast-path,
// strips fully sequential — cross-strip operand sharing spilled 4x: r5/r7/r8/r11) ;
// GEMM2 (fp32 + bias).  No XCD swizzle (r9: doubles FETCH).  8-phase GEMM closed
// (r2 raced via spill-corrupted vmcnt; r13 correct but slower: 1.5-round tail @1blk/CU).

typedef unsigned short u16;
typedef short bf16x8 __attribute__((ext_vector_type(8)));
typedef unsigned short u16x8 __attribute__((ext_vector_type(8)));
typedef float f32x4 __attribute__((ext_vector_type(4)));

#define MFMA16(a, b, c) __builtin_amdgcn_mfma_f32_16x16x32_bf16((a), (b), (c), 0, 0, 0)

__device__ __forceinline__ float b2f(u16 u) { return __uint_as_float(((unsigned)u) << 16); }
__device__ __forceinline__ u16 f2b(float f) {
    unsigned x = __float_as_uint(f);
    return (u16)((x + 0x7fffu + ((x >> 16) & 1u)) >> 16);
}
__device__ __forceinline__ void gload16(const u16* g, u16* lds) {
    __builtin_amdgcn_global_load_lds((__attribute__((address_space(1))) void*)g,
                                     (__attribute__((address_space(3))) void*)lds,
                                     16, 0, 0);
}

// ------- fp32 -> bf16 conversion (3 tensors) + rope tables, one dispatch -------
__global__ __launch_bounds__(256) void cvt3(const float* __restrict__ x,
                                            const float* __restrict__ wqkv,
                                            const float* __restrict__ wproj,
                                            u16* __restrict__ xo, u16* __restrict__ qo,
                                            u16* __restrict__ po,
                                            float* __restrict__ cosT,
                                            float* __restrict__ sinT) {
    const int bx = blockIdx.x;
    if (bx >= 12288) {  // rope tables: 512 blocks, 131072 entries
        int idx = (bx - 12288) * 256 + threadIdx.x;
        int n = idx >> 6, i = idx & 63;
        float inv = powf(10000.0f, -(float)(2 * i) / 128.0f);
        float ang = (float)n * inv;
        cosT[idx] = cosf(ang);
        sinT[idx] = sinf(ang);
        return;
    }
    const float* src;
    u16* dst;
    size_t base;
    if (bx < 4096) {
        src = x; dst = xo; base = (size_t)bx * 256;
    } else if (bx < 10240) {
        src = wqkv; dst = qo; base = (size_t)(bx - 4096) * 256;
    } else {
        src = wproj; dst = po; base = (size_t)(bx - 10240) * 256;
    }
    size_t i = base + threadIdx.x;
    float4 a = ((const float4*)src)[2 * i];
    float4 b = ((const float4*)src)[2 * i + 1];
    u16x8 o;
    o[0] = f2b(a.x); o[1] = f2b(a.y); o[2] = f2b(a.z); o[3] = f2b(a.w);
    o[4] = f2b(b.x); o[5] = f2b(b.y); o[6] = f2b(b.z); o[7] = f2b(b.w);
    ((u16x8*)dst)[i] = o;
}

// ---------------- GEMM1 fused: qkv = x @ Wqkv^T, epilogue rope/transpose ----------------
// grid (32, 48).  sec = by>>4 (0=q,1=k,2=v), head = by&15.  V epilogue stores C
// TRANSPOSED into LDS (smem[d*136 + token]): write 4-way-scattered, read row-wise b128
// conflict-free (r12 verified: conflicts 4.19M -> 459K).
__global__ __launch_bounds__(256, 2) void gemm1_fused(
    const u16* __restrict__ A, const u16* __restrict__ B,
    const float* __restrict__ cosT, const float* __restrict__ sinT,
    u16* __restrict__ Q, u16* __restrict__ Ko, u16* __restrict__ VT) {
    __shared__ u16 smem[17408];  // K-loop: As|Bs in [0,16384); epilogue: 128x136
    u16* As = smem;
    u16* Bs = smem + 8192;
    const int K = 2048;
    const int tx = threadIdx.x;
    const int w = tx >> 6, l = tx & 63;
    const int fr = l & 15, fg = l >> 4;
    const int wr = w >> 1, wc = w & 1;
    const long row0 = (long)blockIdx.x * 128;
    const long col0 = (long)blockIdx.y * 128;
    f32x4 acc[4][4] = {};
    int rs[4], ss[4];
#pragma unroll
    for (int i = 0; i < 4; ++i) {
        int c = i * 256 + tx;
        rs[i] = c >> 3;
        ss[i] = (c & 7) ^ ((c >> 3) & 7);
    }
    for (int kt = 0; kt < 32; ++kt) {
        const long k0 = (long)kt << 6;
        __syncthreads();
#pragma unroll
        for (int i = 0; i < 4; ++i)
            gload16(A + (row0 + rs[i]) * K + k0 + ss[i] * 8, &As[(i * 256 + w * 64) * 8]);
#pragma unroll
        for (int i = 0; i < 4; ++i)
            gload16(B + (col0 + rs[i]) * K + k0 + ss[i] * 8, &Bs[(i * 256 + w * 64) * 8]);
        __syncthreads();
#pragma unroll
        for (int kk = 0; kk < 2; ++kk) {
            bf16x8 af[4], bfv[4];
#pragma unroll
            for (int m = 0; m < 4; ++m) {
                int r = wr * 64 + m * 16 + fr;
                af[m] = *(const bf16x8*)&As[r * 64 + (((kk * 4 + fg) ^ (r & 7)) << 3)];
            }
#pragma unroll
            for (int n = 0; n < 4; ++n) {
                int r = wc * 64 + n * 16 + fr;
                bfv[n] = *(const bf16x8*)&Bs[r * 64 + (((kk * 4 + fg) ^ (r & 7)) << 3)];
            }
#pragma unroll
            for (int m = 0; m < 4; ++m)
#pragma unroll
                for (int n = 0; n < 4; ++n) acc[m][n] = MFMA16(af[m], bfv[n], acc[m][n]);
        }
    }
    // ---- epilogue ----
    const int sec = blockIdx.y >> 4;        // 0=q, 1=k, 2=v
    const int h = blockIdx.y & 15;
    const int b = (int)(row0 >> 11);
    const int n0 = (int)(row0 & 2047);
    const int bh = b * 16 + h;
    __syncthreads();  // all waves done reading As/Bs
    if (sec < 2) {
#pragma unroll
        for (int m = 0; m < 4; ++m)
#pragma unroll
            for (int n = 0; n < 4; ++n)
#pragma unroll
                for (int r = 0; r < 4; ++r)
                    smem[(wr * 64 + m * 16 + fg * 4 + r) * 136 + wc * 64 + n * 16 + fr] =
                        f2b(acc[m][n][r]);
        __syncthreads();
        const float SC = (sec == 0) ? 0.08838834764831844f : 1.0f;  // 1/sqrt(128) for q
        u16* dstb = (sec == 0 ? Q : Ko) + ((size_t)bh * 2048 + n0) * 128;
#pragma unroll
        for (int i = 0; i < 4; ++i) {
            int cid = i * 256 + tx;
            int rowl = cid >> 3, g = cid & 7;
            int d0 = g * 8;
            int ntok = n0 + rowl;
            u16x8 t1 = *(const u16x8*)&smem[rowl * 136 + d0];
            u16x8 t2 = *(const u16x8*)&smem[rowl * 136 + 64 + d0];
            float4 c1 = *(const float4*)&cosT[ntok * 64 + d0];
            float4 c2 = *(const float4*)&cosT[ntok * 64 + d0 + 4];
            float4 s1 = *(const float4*)&sinT[ntok * 64 + d0];
            float4 s2 = *(const float4*)&sinT[ntok * 64 + d0 + 4];
            float cc[8] = {c1.x, c1.y, c1.z, c1.w, c2.x, c2.y, c2.z, c2.w};
            float ssn[8] = {s1.x, s1.y, s1.z, s1.w, s2.x, s2.y, s2.z, s2.w};
            u16x8 o1, o2;
#pragma unroll
            for (int j = 0; j < 8; ++j) {
                float a = b2f(t1[j]), bb = b2f(t2[j]);
                o1[j] = f2b((a * cc[j] - bb * ssn[j]) * SC);
                o2[j] = f2b((a * ssn[j] + bb * cc[j]) * SC);
            }
            *(u16x8*)&dstb[(size_t)rowl * 128 + d0] = o1;
            *(u16x8*)&dstb[(size_t)rowl * 128 + 64 + d0] = o2;
        }
    } else {
#pragma unroll
        for (int m = 0; m < 4; ++m)
#pragma unroll
            for (int n = 0; n < 4; ++n)
#pragma unroll
                for (int r = 0; r < 4; ++r)
                    smem[(wc * 64 + n * 16 + fr) * 136 + wr * 64 + m * 16 + fg * 4 + r] =
                        f2b(acc[m][n][r]);
        __syncthreads();
#pragma unroll
        for (int i = 0; i < 8; ++i) {
            int cid = i * 256 + tx;
            int d = cid >> 4, g = cid & 15;
            *(u16x8*)&VT[((size_t)bh * 128 + d) * 2048 + n0 + g * 8] =
                *(const u16x8*)&smem[d * 136 + g * 8];
        }
    }
}

// ---------------- NT GEMM (BK=64, conflict-free) for GEMM2 ----------------
__global__ __launch_bounds__(256, 2) void gemm_nt_f32(const u16* __restrict__ A,
                                                      const u16* __restrict__ B,
                                                      float* __restrict__ C,
                                                      const float* __restrict__ bias,
                                                      int Ncols, int K) {
    __shared__ u16 As[128 * 64];
    __shared__ u16 Bs[128 * 64];
    const int tx = threadIdx.x;
    const int w = tx >> 6, l = tx & 63;
    const int fr = l & 15, fg = l >> 4;
    const int wr = w >> 1, wc = w & 1;
    const long row0 = (long)blockIdx.x * 128;
    const long col0 = (long)blockIdx.y * 128;
    f32x4 acc[4][4] = {};
    const int nk = K >> 6;
    int rs[4], ss[4];
#pragma unroll
    for (int i = 0; i < 4; ++i) {
        int c = i * 256 + tx;
        rs[i] = c >> 3;
        ss[i] = (c & 7) ^ ((c >> 3) & 7);
    }
    for (int kt = 0; kt < nk; ++kt) {
        const long k0 = (long)kt << 6;
        __syncthreads();
#pragma unroll
        for (int i = 0; i < 4; ++i)
            gload16(A + (row0 + rs[i]) * K + k0 + ss[i] * 8, &As[(i * 256 + w * 64) * 8]);
#pragma unroll
        for (int i = 0; i < 4; ++i)
            gload16(B + (col0 + rs[i]) * K + k0 + ss[i] * 8, &Bs[(i * 256 + w * 64) * 8]);
        __syncthreads();
#pragma unroll
        for (int kk = 0; kk < 2; ++kk) {
            bf16x8 af[4], bfv[4];
#pragma unroll
            for (int m = 0; m < 4; ++m) {
                int r = wr * 64 + m * 16 + fr;
                af[m] = *(const bf16x8*)&As[r * 64 + (((kk * 4 + fg) ^ (r & 7)) << 3)];
            }
#pragma unroll
            for (int n = 0; n < 4; ++n) {
                int r = wc * 64 + n * 16 + fr;
                bfv[n] = *(const bf16x8*)&Bs[r * 64 + (((kk * 4 + fg) ^ (r & 7)) << 3)];
            }
#pragma unroll
            for (int m = 0; m < 4; ++m)
#pragma unroll
                for (int n = 0; n < 4; ++n) acc[m][n] = MFMA16(af[m], bfv[n], acc[m][n]);
        }
    }
#pragma unroll
    for (int m = 0; m < 4; ++m)
#pragma unroll
        for (int n = 0; n < 4; ++n)
#pragma unroll
            for (int r = 0; r < 4; ++r) {
                long row = row0 + wr * 64 + m * 16 + fg * 4 + r;
                long col = col0 + wc * 64 + n * 16 + fr;
                C[row * Ncols + col] = acc[m][n][r] + bias[col];
            }
}

// ---------------- Flash attention (paired strips + fast-path, fully sequential) -------
__global__ __launch_bounds__(256, 2) void attn_k(const u16* __restrict__ Q,
                                                 const u16* __restrict__ K,
                                                 const u16* __restrict__ VT,
                                                 u16* __restrict__ O,
                                                 const int* __restrict__ L) {
    const int bh = blockIdx.y, b = bh >> 4, h = bh & 15;
    const int qx = blockIdx.x;
    const int qb0 = qx << 6, qb1 = (31 - qx) << 6;
    const int tx = threadIdx.x;
    const int w = tx >> 6, l = tx & 63;
    const int fr = l & 15, fg = l >> 4;
    const int Lb = L[b];
    __shared__ u16 Ks[2][64 * 128];
    __shared__ u16 Vs[2][128 * 64];
    __shared__ u16 Ps[4][16 * 72];
    const u16* Qh = Q + (size_t)bh * 2048 * 128;
    const u16* Kh = K + (size_t)bh * 2048 * 128;
    const u16* Vh = VT + (size_t)bh * 128 * 2048;
    bf16x8 aq0[4], aq1[4];
#pragma unroll
    for (int kc = 0; kc < 4; ++kc) {
        aq0[kc] = *(const bf16x8*)&Qh[(size_t)(qb0 + w * 16 + fr) * 128 + kc * 32 + fg * 8];
        aq1[kc] = *(const bf16x8*)&Qh[(size_t)(qb1 + w * 16 + fr) * 128 + kc * 32 + fg * 8];
    }
    f32x4 accO0[8] = {}, accO1[8] = {};
    float mr0[4] = {-1e30f, -1e30f, -1e30f, -1e30f};
    float mr1[4] = {-1e30f, -1e30f, -1e30f, -1e30f};
    float sr0[4] = {0.f, 0.f, 0.f, 0.f};
    float sr1[4] = {0.f, 0.f, 0.f, 0.f};
    const int kmax = min(qb1 + 63, Lb - 1);
    const int nkt = (kmax >> 6) + 1;

    auto stage_tile = [&](int kt0, int buf) {
#pragma unroll
        for (int i = 0; i < 4; ++i) {
            int c = i * 256 + tx;
            int row = c >> 4, cp = c & 15;
            gload16(Kh + (size_t)(kt0 + row) * 128 + ((cp ^ (row & 7)) << 3),
                    &Ks[buf][(i * 256 + w * 64) * 8]);
        }
#pragma unroll
        for (int i = 0; i < 4; ++i) {
            int c = i * 256 + tx;
            int row = c >> 3, cp = c & 7;
            gload16(Vh + (size_t)row * 2048 + kt0 + ((cp ^ (row & 7)) << 3),
                    &Vs[buf][(i * 256 + w * 64) * 8]);
        }
    };

    auto do_strip = [&](const bf16x8 (&aqs)[4], float (&mr)[4], float (&sr)[4],
                        f32x4 (&aO)[8], int qgb, int kt0, const u16* Ksb,
                        const u16* Vsb) {
        f32x4 accS[4];
#pragma unroll
        for (int st = 0; st < 4; ++st) {
            f32x4 z = {0.f, 0.f, 0.f, 0.f};
            accS[st] = z;
            int key = st * 16 + fr;
#pragma unroll
            for (int kc = 0; kc < 4; ++kc) {
                bf16x8 bk = *(const bf16x8*)&Ksb[key * 128 + (((kc * 4 + fg) ^ (key & 7)) << 3)];
                accS[st] = MFMA16(aqs[kc], bk, accS[st]);
            }
        }
        float sv[4][4];
        if ((kt0 + 63 <= qgb) && (kt0 + 63 < Lb)) {
#pragma unroll
            for (int st = 0; st < 4; ++st)
#pragma unroll
                for (int r = 0; r < 4; ++r) sv[st][r] = accS[st][r];
        } else {
#pragma unroll
            for (int st = 0; st < 4; ++st)
#pragma unroll
                for (int r = 0; r < 4; ++r) {
                    int key = kt0 + st * 16 + fr;
                    int qg = qgb + fg * 4 + r;
                    sv[st][r] = (key <= qg && key < Lb) ? accS[st][r] : -1e30f;
                }
        }
        float alpha[4], pr[4][4];
#pragma unroll
        for (int r = 0; r < 4; ++r) {
            float lm = fmaxf(fmaxf(sv[0][r], sv[1][r]), fmaxf(sv[2][r], sv[3][r]));
            lm = fmaxf(lm, __shfl_xor(lm, 1));
            lm = fmaxf(lm, __shfl_xor(lm, 2));
            lm = fmaxf(lm, __shfl_xor(lm, 4));
            lm = fmaxf(lm, __shfl_xor(lm, 8));
            float mn = fmaxf(mr[r], lm);
            alpha[r] = exp2f((mr[r] - mn) * 1.44269504f);
            float ls = 0.f;
#pragma unroll
            for (int st = 0; st < 4; ++st) {
                float p = exp2f((sv[st][r] - mn) * 1.44269504f);
                pr[st][r] = p;
                ls += p;
            }
            ls += __shfl_xor(ls, 1);
            ls += __shfl_xor(ls, 2);
            ls += __shfl_xor(ls, 4);
            ls += __shfl_xor(ls, 8);
            sr[r] = sr[r] * alpha[r] + ls;
            mr[r] = mn;
        }
#pragma unroll
        for (int n = 0; n < 8; ++n)
#pragma unroll
            for (int r = 0; r < 4; ++r) aO[n][r] *= alpha[r];
#pragma unroll
        for (int st = 0; st < 4; ++st)
#pragma unroll
            for (int r = 0; r < 4; ++r)
                Ps[w][(fg * 4 + r) * 72 + st * 16 + fr] = f2b(pr[st][r]);
#pragma unroll
        for (int ks = 0; ks < 2; ++ks) {
            bf16x8 ap = *(const bf16x8*)&Ps[w][fr * 72 + ks * 32 + fg * 8];
#pragma unroll
            for (int n = 0; n < 8; ++n) {
                int d = n * 16 + fr;
                bf16x8 bv = *(const bf16x8*)&Vsb[d * 64 + (((ks * 4 + fg) ^ (d & 7)) << 3)];
                aO[n] = MFMA16(ap, bv, aO[n]);
            }
        }
    };

    stage_tile(0, 0);
    int cur = 0;
    for (int kt = 0; kt < nkt; ++kt) {
        const int kt0 = kt << 6;
        __syncthreads();
        if (kt + 1 < nkt) stage_tile((kt + 1) << 6, cur ^ 1);
        if (kt <= qx)
            do_strip(aq0, mr0, sr0, accO0, qb0 + w * 16, kt0, Ks[cur], Vs[cur]);
        do_strip(aq1, mr1, sr1, accO1, qb1 + w * 16, kt0, Ks[cur], Vs[cur]);
        cur ^= 1;
    }
    float inv0[4], inv1[4];
#pragma unroll
    for (int r = 0; r < 4; ++r) {
        inv0[r] = 1.0f / sr0[r];
        inv1[r] = 1.0f / sr1[r];
    }
#pragma unroll
    for (int n = 0; n < 8; ++n)
#pragma unroll
        for (int r = 0; r < 4; ++r) {
            int d = n * 16 + fr;
            int q0 = qb0 + w * 16 + fg * 4 + r;
            int q1 = qb1 + w * 16 + fg * 4 + r;
            O[((size_t)(b * 2048 + q0)) * 2048 + h * 128 + d] = f2b(accO0[n][r] * inv0[r]);
            O[((size_t)(b * 2048 + q1)) * 2048 + h * 128 + d] = f2b(accO1[n][r] * inv1[r]);
        }
}

extern "C" void kernel_launch(void* const* d_in, const int* in_sizes, int n_in,
                              void* d_out, int out_size, void* d_ws, size_t ws_size,
                              hipStream_t stream) {
    const float* x = (const float*)d_in[0];
    const float* Wqkv = (const float*)d_in[1];
    const float* Wproj = (const float*)d_in[2];
    const float* bproj = (const float*)d_in[3];
    const int* L = (const int*)d_in[4];
    float* out = (float*)d_out;

    char* p = (char*)d_ws;
    u16* xbf = (u16*)(p + 0);                // reused as Ob after GEMM1
    u16* wqkvbf = (u16*)(p + 16777216);
    u16* wprojbf = (u16*)(p + 41943040);
    u16* Qb = (u16*)(p + 50331648);
    u16* Kb = (u16*)(p + 100663296);
    u16* VTb = (u16*)(p + 117440512);
    float* cosT = (float*)(p + 134217728);
    float* sinT = (float*)(p + 134742016);
    u16* Ob = xbf;

    cvt3<<<12800, 256, 0, stream>>>(x, Wqkv, Wproj, xbf, wqkvbf, wprojbf, cosT, sinT);
    gemm1_fused<<<dim3(32, 48), 256, 0, stream>>>(xbf, wqkvbf, cosT, sinT, Qb, Kb, VTb);
    attn_k<<<dim3(16, 32), 256, 0, stream>>>(Qb, Kb, VTb, Ob, L);
    gemm_nt_f32<<<dim3(32, 16), 256, 0, stream>>>(Ob, wprojbf, out, bproj, 2048, 2048);
}

// Round 15
// 236.594 us; speedup vs baseline: 1.1841x; 1.0054x over previous
//
#include <hip/hip_runtime.h>
#include <hip/hip_bf16.h>

// Problem: B=2, N=2048, D=2048, h=16, hd=128.  All dims hardcoded.
// Pipeline: cvt3+tables (one dispatch) ; GEMM1 fused (m97-family BK=64 conflict-free;
// epilogue ropes q/k + transposes v) ; flash attention (paired strips, dbuf, fast-path,
// strips fully sequential — cross-strip operand sharing spilled 4x; NEW: per-lane
// deferred softmax-denominator reduce + setprio around MFMA clusters) ;
// GEMM2 (fp32 + bias).  No XCD swizzle (r9).  8-phase GEMM closed (r2 race, r13 slower).

typedef unsigned short u16;
typedef short bf16x8 __attribute__((ext_vector_type(8)));
typedef unsigned short u16x8 __attribute__((ext_vector_type(8)));
typedef float f32x4 __attribute__((ext_vector_type(4)));

#define MFMA16(a, b, c) __builtin_amdgcn_mfma_f32_16x16x32_bf16((a), (b), (c), 0, 0, 0)

__device__ __forceinline__ float b2f(u16 u) { return __uint_as_float(((unsigned)u) << 16); }
__device__ __forceinline__ u16 f2b(float f) {
    unsigned x = __float_as_uint(f);
    return (u16)((x + 0x7fffu + ((x >> 16) & 1u)) >> 16);
}
__device__ __forceinline__ void gload16(const u16* g, u16* lds) {
    __builtin_amdgcn_global_load_lds((__attribute__((address_space(1))) void*)g,
                                     (__attribute__((address_space(3))) void*)lds,
                                     16, 0, 0);
}

// ------- fp32 -> bf16 conversion (3 tensors) + rope tables, one dispatch -------
__global__ __launch_bounds__(256) void cvt3(const float* __restrict__ x,
                                            const float* __restrict__ wqkv,
                                            const float* __restrict__ wproj,
                                            u16* __restrict__ xo, u16* __restrict__ qo,
                                            u16* __restrict__ po,
                                            float* __restrict__ cosT,
                                            float* __restrict__ sinT) {
    const int bx = blockIdx.x;
    if (bx >= 12288) {  // rope tables: 512 blocks, 131072 entries
        int idx = (bx - 12288) * 256 + threadIdx.x;
        int n = idx >> 6, i = idx & 63;
        float inv = powf(10000.0f, -(float)(2 * i) / 128.0f);
        float ang = (float)n * inv;
        cosT[idx] = cosf(ang);
        sinT[idx] = sinf(ang);
        return;
    }
    const float* src;
    u16* dst;
    size_t base;
    if (bx < 4096) {
        src = x; dst = xo; base = (size_t)bx * 256;
    } else if (bx < 10240) {
        src = wqkv; dst = qo; base = (size_t)(bx - 4096) * 256;
    } else {
        src = wproj; dst = po; base = (size_t)(bx - 10240) * 256;
    }
    size_t i = base + threadIdx.x;
    float4 a = ((const float4*)src)[2 * i];
    float4 b = ((const float4*)src)[2 * i + 1];
    u16x8 o;
    o[0] = f2b(a.x); o[1] = f2b(a.y); o[2] = f2b(a.z); o[3] = f2b(a.w);
    o[4] = f2b(b.x); o[5] = f2b(b.y); o[6] = f2b(b.z); o[7] = f2b(b.w);
    ((u16x8*)dst)[i] = o;
}

// ---------------- GEMM1 fused: qkv = x @ Wqkv^T, epilogue rope/transpose ----------------
__global__ __launch_bounds__(256, 2) void gemm1_fused(
    const u16* __restrict__ A, const u16* __restrict__ B,
    const float* __restrict__ cosT, const float* __restrict__ sinT,
    u16* __restrict__ Q, u16* __restrict__ Ko, u16* __restrict__ VT) {
    __shared__ u16 smem[17408];  // K-loop: As|Bs in [0,16384); epilogue: 128x136
    u16* As = smem;
    u16* Bs = smem + 8192;
    const int K = 2048;
    const int tx = threadIdx.x;
    const int w = tx >> 6, l = tx & 63;
    const int fr = l & 15, fg = l >> 4;
    const int wr = w >> 1, wc = w & 1;
    const long row0 = (long)blockIdx.x * 128;
    const long col0 = (long)blockIdx.y * 128;
    f32x4 acc[4][4] = {};
    int rs[4], ss[4];
#pragma unroll
    for (int i = 0; i < 4; ++i) {
        int c = i * 256 + tx;
        rs[i] = c >> 3;
        ss[i] = (c & 7) ^ ((c >> 3) & 7);
    }
    for (int kt = 0; kt < 32; ++kt) {
        const long k0 = (long)kt << 6;
        __syncthreads();
#pragma unroll
        for (int i = 0; i < 4; ++i)
            gload16(A + (row0 + rs[i]) * K + k0 + ss[i] * 8, &As[(i * 256 + w * 64) * 8]);
#pragma unroll
        for (int i = 0; i < 4; ++i)
            gload16(B + (col0 + rs[i]) * K + k0 + ss[i] * 8, &Bs[(i * 256 + w * 64) * 8]);
        __syncthreads();
#pragma unroll
        for (int kk = 0; kk < 2; ++kk) {
            bf16x8 af[4], bfv[4];
#pragma unroll
            for (int m = 0; m < 4; ++m) {
                int r = wr * 64 + m * 16 + fr;
                af[m] = *(const bf16x8*)&As[r * 64 + (((kk * 4 + fg) ^ (r & 7)) << 3)];
            }
#pragma unroll
            for (int n = 0; n < 4; ++n) {
                int r = wc * 64 + n * 16 + fr;
                bfv[n] = *(const bf16x8*)&Bs[r * 64 + (((kk * 4 + fg) ^ (r & 7)) << 3)];
            }
#pragma unroll
            for (int m = 0; m < 4; ++m)
#pragma unroll
                for (int n = 0; n < 4; ++n) acc[m][n] = MFMA16(af[m], bfv[n], acc[m][n]);
        }
    }
    // ---- epilogue ----
    const int sec = blockIdx.y >> 4;        // 0=q, 1=k, 2=v
    const int h = blockIdx.y & 15;
    const int b = (int)(row0 >> 11);
    const int n0 = (int)(row0 & 2047);
    const int bh = b * 16 + h;
    __syncthreads();  // all waves done reading As/Bs
    if (sec < 2) {
#pragma unroll
        for (int m = 0; m < 4; ++m)
#pragma unroll
            for (int n = 0; n < 4; ++n)
#pragma unroll
                for (int r = 0; r < 4; ++r)
                    smem[(wr * 64 + m * 16 + fg * 4 + r) * 136 + wc * 64 + n * 16 + fr] =
                        f2b(acc[m][n][r]);
        __syncthreads();
        const float SC = (sec == 0) ? 0.08838834764831844f : 1.0f;  // 1/sqrt(128) for q
        u16* dstb = (sec == 0 ? Q : Ko) + ((size_t)bh * 2048 + n0) * 128;
#pragma unroll
        for (int i = 0; i < 4; ++i) {
            int cid = i * 256 + tx;
            int rowl = cid >> 3, g = cid & 7;
            int d0 = g * 8;
            int ntok = n0 + rowl;
            u16x8 t1 = *(const u16x8*)&smem[rowl * 136 + d0];
            u16x8 t2 = *(const u16x8*)&smem[rowl * 136 + 64 + d0];
            float4 c1 = *(const float4*)&cosT[ntok * 64 + d0];
            float4 c2 = *(const float4*)&cosT[ntok * 64 + d0 + 4];
            float4 s1 = *(const float4*)&sinT[ntok * 64 + d0];
            float4 s2 = *(const float4*)&sinT[ntok * 64 + d0 + 4];
            float cc[8] = {c1.x, c1.y, c1.z, c1.w, c2.x, c2.y, c2.z, c2.w};
            float ssn[8] = {s1.x, s1.y, s1.z, s1.w, s2.x, s2.y, s2.z, s2.w};
            u16x8 o1, o2;
#pragma unroll
            for (int j = 0; j < 8; ++j) {
                float a = b2f(t1[j]), bb = b2f(t2[j]);
                o1[j] = f2b((a * cc[j] - bb * ssn[j]) * SC);
                o2[j] = f2b((a * ssn[j] + bb * cc[j]) * SC);
            }
            *(u16x8*)&dstb[(size_t)rowl * 128 + d0] = o1;
            *(u16x8*)&dstb[(size_t)rowl * 128 + 64 + d0] = o2;
        }
    } else {
#pragma unroll
        for (int m = 0; m < 4; ++m)
#pragma unroll
            for (int n = 0; n < 4; ++n)
#pragma unroll
                for (int r = 0; r < 4; ++r)
                    smem[(wc * 64 + n * 16 + fr) * 136 + wr * 64 + m * 16 + fg * 4 + r] =
                        f2b(acc[m][n][r]);
        __syncthreads();
#pragma unroll
        for (int i = 0; i < 8; ++i) {
            int cid = i * 256 + tx;
            int d = cid >> 4, g = cid & 15;
            *(u16x8*)&VT[((size_t)bh * 128 + d) * 2048 + n0 + g * 8] =
                *(const u16x8*)&smem[d * 136 + g * 8];
        }
    }
}

// ---------------- NT GEMM (BK=64, conflict-free) for GEMM2 ----------------
__global__ __launch_bounds__(256, 2) void gemm_nt_f32(const u16* __restrict__ A,
                                                      const u16* __restrict__ B,
                                                      float* __restrict__ C,
                                                      const float* __restrict__ bias,
                                                      int Ncols, int K) {
    __shared__ u16 As[128 * 64];
    __shared__ u16 Bs[128 * 64];
    const int tx = threadIdx.x;
    const int w = tx >> 6, l = tx & 63;
    const int fr = l & 15, fg = l >> 4;
    const int wr = w >> 1, wc = w & 1;
    const long row0 = (long)blockIdx.x * 128;
    const long col0 = (long)blockIdx.y * 128;
    f32x4 acc[4][4] = {};
    const int nk = K >> 6;
    int rs[4], ss[4];
#pragma unroll
    for (int i = 0; i < 4; ++i) {
        int c = i * 256 + tx;
        rs[i] = c >> 3;
        ss[i] = (c & 7) ^ ((c >> 3) & 7);
    }
    for (int kt = 0; kt < nk; ++kt) {
        const long k0 = (long)kt << 6;
        __syncthreads();
#pragma unroll
        for (int i = 0; i < 4; ++i)
            gload16(A + (row0 + rs[i]) * K + k0 + ss[i] * 8, &As[(i * 256 + w * 64) * 8]);
#pragma unroll
        for (int i = 0; i < 4; ++i)
            gload16(B + (col0 + rs[i]) * K + k0 + ss[i] * 8, &Bs[(i * 256 + w * 64) * 8]);
        __syncthreads();
#pragma unroll
        for (int kk = 0; kk < 2; ++kk) {
            bf16x8 af[4], bfv[4];
#pragma unroll
            for (int m = 0; m < 4; ++m) {
                int r = wr * 64 + m * 16 + fr;
                af[m] = *(const bf16x8*)&As[r * 64 + (((kk * 4 + fg) ^ (r & 7)) << 3)];
            }
#pragma unroll
            for (int n = 0; n < 4; ++n) {
                int r = wc * 64 + n * 16 + fr;
                bfv[n] = *(const bf16x8*)&Bs[r * 64 + (((kk * 4 + fg) ^ (r & 7)) << 3)];
            }
#pragma unroll
            for (int m = 0; m < 4; ++m)
#pragma unroll
                for (int n = 0; n < 4; ++n) acc[m][n] = MFMA16(af[m], bfv[n], acc[m][n]);
        }
    }
#pragma unroll
    for (int m = 0; m < 4; ++m)
#pragma unroll
        for (int n = 0; n < 4; ++n)
#pragma unroll
            for (int r = 0; r < 4; ++r) {
                long row = row0 + wr * 64 + m * 16 + fg * 4 + r;
                long col = col0 + wc * 64 + n * 16 + fr;
                C[row * Ncols + col] = acc[m][n][r] + bias[col];
            }
}

// ---------------- Flash attention (paired strips + fast-path, fully sequential) -------
// NEW vs r14: (1) softmax denominator kept as PER-LANE partial (alpha is row-uniform,
// sum is linear) — the 4-shuffle row reduce runs ONCE in the epilogue instead of every
// tile (saves 16 shfl/strip-tile on the contended LDS pipe); (2) setprio(1) around the
// QK and PV MFMA clusters (T5, m191 attn-positive; 2 blocks/CU gives wave diversity).
__global__ __launch_bounds__(256, 2) void attn_k(const u16* __restrict__ Q,
                                                 const u16* __restrict__ K,
                                                 const u16* __restrict__ VT,
                                                 u16* __restrict__ O,
                                                 const int* __restrict__ L) {
    const int bh = blockIdx.y, b = bh >> 4, h = bh & 15;
    const int qx = blockIdx.x;
    const int qb0 = qx << 6, qb1 = (31 - qx) << 6;
    const int tx = threadIdx.x;
    const int w = tx >> 6, l = tx & 63;
    const int fr = l & 15, fg = l >> 4;
    const int Lb = L[b];
    __shared__ u16 Ks[2][64 * 128];
    __shared__ u16 Vs[2][128 * 64];
    __shared__ u16 Ps[4][16 * 72];
    const u16* Qh = Q + (size_t)bh * 2048 * 128;
    const u16* Kh = K + (size_t)bh * 2048 * 128;
    const u16* Vh = VT + (size_t)bh * 128 * 2048;
    bf16x8 aq0[4], aq1[4];
#pragma unroll
    for (int kc = 0; kc < 4; ++kc) {
        aq0[kc] = *(const bf16x8*)&Qh[(size_t)(qb0 + w * 16 + fr) * 128 + kc * 32 + fg * 8];
        aq1[kc] = *(const bf16x8*)&Qh[(size_t)(qb1 + w * 16 + fr) * 128 + kc * 32 + fg * 8];
    }
    f32x4 accO0[8] = {}, accO1[8] = {};
    float mr0[4] = {-1e30f, -1e30f, -1e30f, -1e30f};
    float mr1[4] = {-1e30f, -1e30f, -1e30f, -1e30f};
    float sr0[4] = {0.f, 0.f, 0.f, 0.f};  // PER-LANE partial denominators
    float sr1[4] = {0.f, 0.f, 0.f, 0.f};
    const int kmax = min(qb1 + 63, Lb - 1);
    const int nkt = (kmax >> 6) + 1;

    auto stage_tile = [&](int kt0, int buf) {
#pragma unroll
        for (int i = 0; i < 4; ++i) {
            int c = i * 256 + tx;
            int row = c >> 4, cp = c & 15;
            gload16(Kh + (size_t)(kt0 + row) * 128 + ((cp ^ (row & 7)) << 3),
                    &Ks[buf][(i * 256 + w * 64) * 8]);
        }
#pragma unroll
        for (int i = 0; i < 4; ++i) {
            int c = i * 256 + tx;
            int row = c >> 3, cp = c & 7;
            gload16(Vh + (size_t)row * 2048 + kt0 + ((cp ^ (row & 7)) << 3),
                    &Vs[buf][(i * 256 + w * 64) * 8]);
        }
    };

    auto do_strip = [&](const bf16x8 (&aqs)[4], float (&mr)[4], float (&sr)[4],
                        f32x4 (&aO)[8], int qgb, int kt0, const u16* Ksb,
                        const u16* Vsb) {
        f32x4 accS[4];
        __builtin_amdgcn_s_setprio(1);
#pragma unroll
        for (int st = 0; st < 4; ++st) {
            f32x4 z = {0.f, 0.f, 0.f, 0.f};
            accS[st] = z;
            int key = st * 16 + fr;
#pragma unroll
            for (int kc = 0; kc < 4; ++kc) {
                bf16x8 bk = *(const bf16x8*)&Ksb[key * 128 + (((kc * 4 + fg) ^ (key & 7)) << 3)];
                accS[st] = MFMA16(aqs[kc], bk, accS[st]);
            }
        }
        __builtin_amdgcn_s_setprio(0);
        float sv[4][4];
        if ((kt0 + 63 <= qgb) && (kt0 + 63 < Lb)) {
#pragma unroll
            for (int st = 0; st < 4; ++st)
#pragma unroll
                for (int r = 0; r < 4; ++r) sv[st][r] = accS[st][r];
        } else {
#pragma unroll
            for (int st = 0; st < 4; ++st)
#pragma unroll
                for (int r = 0; r < 4; ++r) {
                    int key = kt0 + st * 16 + fr;
                    int qg = qgb + fg * 4 + r;
                    sv[st][r] = (key <= qg && key < Lb) ? accS[st][r] : -1e30f;
                }
        }
        float alpha[4], pr[4][4];
#pragma unroll
        for (int r = 0; r < 4; ++r) {
            float lm = fmaxf(fmaxf(sv[0][r], sv[1][r]), fmaxf(sv[2][r], sv[3][r]));
            lm = fmaxf(lm, __shfl_xor(lm, 1));
            lm = fmaxf(lm, __shfl_xor(lm, 2));
            lm = fmaxf(lm, __shfl_xor(lm, 4));
            lm = fmaxf(lm, __shfl_xor(lm, 8));
            float mn = fmaxf(mr[r], lm);
            alpha[r] = exp2f((mr[r] - mn) * 1.44269504f);
            float ls = 0.f;
#pragma unroll
            for (int st = 0; st < 4; ++st) {
                float p = exp2f((sv[st][r] - mn) * 1.44269504f);
                pr[st][r] = p;
                ls += p;
            }
            // deferred reduce: sr stays per-lane (alpha row-uniform, sum linear)
            sr[r] = sr[r] * alpha[r] + ls;
            mr[r] = mn;
        }
#pragma unroll
        for (int n = 0; n < 8; ++n)
#pragma unroll
            for (int r = 0; r < 4; ++r) aO[n][r] *= alpha[r];
#pragma unroll
        for (int st = 0; st < 4; ++st)
#pragma unroll
            for (int r = 0; r < 4; ++r)
                Ps[w][(fg * 4 + r) * 72 + st * 16 + fr] = f2b(pr[st][r]);
        __builtin_amdgcn_s_setprio(1);
#pragma unroll
        for (int ks = 0; ks < 2; ++ks) {
            bf16x8 ap = *(const bf16x8*)&Ps[w][fr * 72 + ks * 32 + fg * 8];
#pragma unroll
            for (int n = 0; n < 8; ++n) {
                int d = n * 16 + fr;
                bf16x8 bv = *(const bf16x8*)&Vsb[d * 64 + (((ks * 4 + fg) ^ (d & 7)) << 3)];
                aO[n] = MFMA16(ap, bv, aO[n]);
            }
        }
        __builtin_amdgcn_s_setprio(0);
    };

    stage_tile(0, 0);
    int cur = 0;
    for (int kt = 0; kt < nkt; ++kt) {
        const int kt0 = kt << 6;
        __syncthreads();
        if (kt + 1 < nkt) stage_tile((kt + 1) << 6, cur ^ 1);
        if (kt <= qx)
            do_strip(aq0, mr0, sr0, accO0, qb0 + w * 16, kt0, Ks[cur], Vs[cur]);
        do_strip(aq1, mr1, sr1, accO1, qb1 + w * 16, kt0, Ks[cur], Vs[cur]);
        cur ^= 1;
    }
    // epilogue: one cross-lane reduce of the per-lane denominators, then normalize
    float inv0[4], inv1[4];
#pragma unroll
    for (int r = 0; r < 4; ++r) {
        float t0 = sr0[r];
        t0 += __shfl_xor(t0, 1);
        t0 += __shfl_xor(t0, 2);
        t0 += __shfl_xor(t0, 4);
        t0 += __shfl_xor(t0, 8);
        inv0[r] = 1.0f / t0;
        float t1 = sr1[r];
        t1 += __shfl_xor(t1, 1);
        t1 += __shfl_xor(t1, 2);
        t1 += __shfl_xor(t1, 4);
        t1 += __shfl_xor(t1, 8);
        inv1[r] = 1.0f / t1;
    }
#pragma unroll
    for (int n = 0; n < 8; ++n)
#pragma unroll
        for (int r = 0; r < 4; ++r) {
            int d = n * 16 + fr;
            int q0 = qb0 + w * 16 + fg * 4 + r;
            int q1 = qb1 + w * 16 + fg * 4 + r;
            O[((size_t)(b * 2048 + q0)) * 2048 + h * 128 + d] = f2b(accO0[n][r] * inv0[r]);
            O[((size_t)(b * 2048 + q1)) * 2048 + h * 128 + d] = f2b(accO1[n][r] * inv1[r]);
        }
}

extern "C" void kernel_launch(void* const* d_in, const int* in_sizes, int n_in,
                              void* d_out, int out_size, void* d_ws, size_t ws_size,
                              hipStream_t stream) {
    const float* x = (const float*)d_in[0];
    const float* Wqkv = (const float*)d_in[1];
    const float* Wproj = (const float*)d_in[2];
    const float* bproj = (const float*)d_in[3];
    const int* L = (const int*)d_in[4];
    float* out = (float*)d_out;

    char* p = (char*)d_ws;
    u16* xbf = (u16*)(p + 0);                // reused as Ob after GEMM1
    u16* wqkvbf = (u16*)(p + 16777216);
    u16* wprojbf = (u16*)(p + 41943040);
    u16* Qb = (u16*)(p + 50331648);
    u16* Kb = (u16*)(p + 100663296);
    u16* VTb = (u16*)(p + 117440512);
    float* cosT = (float*)(p + 134217728);
    float* sinT = (float*)(p + 134742016);
    u16* Ob = xbf;

    cvt3<<<12800, 256, 0, stream>>>(x, Wqkv, Wproj, xbf, wqkvbf, wprojbf, cosT, sinT);
    gemm1_fused<<<dim3(32, 48), 256, 0, stream>>>(xbf, wqkvbf, cosT, sinT, Qb, Kb, VTb);
    attn_k<<<dim3(16, 32), 256, 0, stream>>>(Qb, Kb, VTb, Ob, L);
    gemm_nt_f32<<<dim3(32, 16), 256, 0, stream>>>(Ob, wprojbf, out, bproj, 2048, 2048);
}